// Round 1
// baseline (1997.805 us; speedup 1.0000x reference)
//
#include <hip/hip_runtime.h>

#define HID   2048
#define INTER 8192
#define NEXP  8
#define NTOK  16384   // 4 * 4096

typedef unsigned short u16;
typedef __bf16 bf16x8 __attribute__((ext_vector_type(8)));
typedef float  floatx4 __attribute__((ext_vector_type(4)));
typedef u16    u16x4   __attribute__((ext_vector_type(4)));

typedef __attribute__((address_space(3))) void       lds_void_t;
typedef const __attribute__((address_space(1))) void gbl_void_t;

__device__ __forceinline__ u16 f2bf(float f) {
    union { float f; unsigned u; } v; v.f = f;
    unsigned r = v.u + 0x7fffu + ((v.u >> 16) & 1u);  // round-to-nearest-even
    return (u16)(r >> 16);
}

__device__ __forceinline__ void load_lds16(const void* g, void* l) {
    __builtin_amdgcn_global_load_lds((gbl_void_t*)g, (lds_void_t*)l, 16, 0, 0);
}

// ---------------------------------------------------------------------------
// Kernel 1: per-token gate logits (fp32) -> top-2 sum scale; write x_bf16 and
// xs_bf16 = x * scale. One wave per token, 4 tokens per block.
// ---------------------------------------------------------------------------
__global__ __launch_bounds__(256) void prep_tokens(
    const float* __restrict__ x, const float* __restrict__ gate,
    u16* __restrict__ xb, u16* __restrict__ xsb)
{
    int token = blockIdx.x * 4 + (threadIdx.x >> 6);
    int lane  = threadIdx.x & 63;
    const float* xr = x + (size_t)token * HID;

    // phase A: logits (lane covers k in [lane*32, lane*32+32))
    float acc[NEXP];
#pragma unroll
    for (int e = 0; e < NEXP; ++e) acc[e] = 0.f;
#pragma unroll
    for (int c = 0; c < 8; ++c) {
        int kbase = lane * 32 + c * 4;
        float4 v = *(const float4*)(xr + kbase);
        float vv[4] = {v.x, v.y, v.z, v.w};
#pragma unroll
        for (int q = 0; q < 4; ++q) {
            const float* g = gate + (size_t)(kbase + q) * NEXP;
            float4 g0 = *(const float4*)(g);
            float4 g1 = *(const float4*)(g + 4);
            acc[0] += vv[q] * g0.x; acc[1] += vv[q] * g0.y;
            acc[2] += vv[q] * g0.z; acc[3] += vv[q] * g0.w;
            acc[4] += vv[q] * g1.x; acc[5] += vv[q] * g1.y;
            acc[6] += vv[q] * g1.z; acc[7] += vv[q] * g1.w;
        }
    }
#pragma unroll
    for (int off = 32; off >= 1; off >>= 1) {
#pragma unroll
        for (int e = 0; e < NEXP; ++e) acc[e] += __shfl_xor(acc[e], off, 64);
    }
    // top-2 sum (matches jax.lax.top_k(...,2).sum())
    float m1 = acc[0], m2 = -3.4e38f;
#pragma unroll
    for (int e = 1; e < NEXP; ++e) {
        float v = acc[e];
        if (v > m1) { m2 = m1; m1 = v; } else if (v > m2) { m2 = v; }
    }
    float scale = m1 + m2;

    // phase B: coalesced cast + scaled cast (row is hot in L1/L2)
    u16* xo  = xb  + (size_t)token * HID;
    u16* xso = xsb + (size_t)token * HID;
#pragma unroll
    for (int c = 0; c < 8; ++c) {
        int idx = (c * 64 + lane) * 4;
        float4 v = *(const float4*)(xr + idx);
        u16x4 b  = { f2bf(v.x), f2bf(v.y), f2bf(v.z), f2bf(v.w) };
        u16x4 bs = { f2bf(v.x * scale), f2bf(v.y * scale),
                     f2bf(v.z * scale), f2bf(v.w * scale) };
        *(u16x4*)(xo  + idx) = b;
        *(u16x4*)(xso + idx) = bs;
    }
}

// ---------------------------------------------------------------------------
// Kernel 2: transpose + cast  in[K][N] fp32 -> out[N][K] bf16
// ---------------------------------------------------------------------------
__global__ __launch_bounds__(256) void transpose_cast(
    const float* __restrict__ in, u16* __restrict__ out, int K, int N)
{
    __shared__ float t[32][33];
    int tx = threadIdx.x & 31;
    int ty = threadIdx.x >> 5;     // 0..7
    int k0 = blockIdx.y * 32, n0 = blockIdx.x * 32;
#pragma unroll
    for (int r = 0; r < 4; ++r)
        t[ty + r * 8][tx] = in[(size_t)(k0 + ty + r * 8) * N + n0 + tx];
    __syncthreads();
#pragma unroll
    for (int r = 0; r < 4; ++r)
        out[(size_t)(n0 + ty + r * 8) * K + k0 + tx] = f2bf(t[tx][ty + r * 8]);
}

// ---------------------------------------------------------------------------
// GEMM core (m97 structure): BM=BN=128, BK=32, 256 threads (2x2 waves),
// A[M][K] bf16 row-major, B[N][K] bf16 row-major (i.e. B^T), fp32 acc.
// ---------------------------------------------------------------------------
#define BM 128
#define BN 128
#define BK 32

// GEMM1: h = bf16(relu(x @ up)^2), h[NTOK][INTER]
__global__ __launch_bounds__(256) void gemm_up(
    const u16* __restrict__ A,   // x_bf16 [NTOK][HID]
    const u16* __restrict__ Bt,  // up^T   [INTER][HID]
    u16* __restrict__ H)         // out    [NTOK][INTER]
{
    __shared__ u16 As[BM * BK];
    __shared__ u16 Bs[BN * BK];
    int tid = threadIdx.x;
    int wid = tid >> 6, lane = tid & 63;
    int wm = wid >> 1, wn = wid & 1;
    int quad = lane >> 4, l16 = lane & 15;
    int m0 = blockIdx.y * BM, n0 = blockIdx.x * BN;

    int c0 = wid, c1 = wid + 4;
    int ar0 = c0 * 16 + (lane >> 2), ar1 = c1 * 16 + (lane >> 2);
    int ac  = (lane & 3) * 8;

    floatx4 acc[4][4];
#pragma unroll
    for (int i = 0; i < 4; ++i)
#pragma unroll
        for (int j = 0; j < 4; ++j) acc[i][j] = (floatx4){0.f, 0.f, 0.f, 0.f};

    const u16* Ab = A  + (size_t)m0 * HID;
    const u16* Bb = Bt + (size_t)n0 * HID;

    for (int kt = 0; kt < HID / BK; ++kt) {
        int kk = kt * BK;
        load_lds16(Ab + (size_t)ar0 * HID + kk + ac, &As[c0 * 512]);
        load_lds16(Ab + (size_t)ar1 * HID + kk + ac, &As[c1 * 512]);
        load_lds16(Bb + (size_t)ar0 * HID + kk + ac, &Bs[c0 * 512]);
        load_lds16(Bb + (size_t)ar1 * HID + kk + ac, &Bs[c1 * 512]);
        __syncthreads();
        bf16x8 af[4], bfr[4];
#pragma unroll
        for (int i = 0; i < 4; ++i)
            af[i] = *(const bf16x8*)(&As[(wm * 64 + i * 16 + l16) * BK + quad * 8]);
#pragma unroll
        for (int j = 0; j < 4; ++j)
            bfr[j] = *(const bf16x8*)(&Bs[(wn * 64 + j * 16 + l16) * BK + quad * 8]);
#pragma unroll
        for (int i = 0; i < 4; ++i)
#pragma unroll
            for (int j = 0; j < 4; ++j)
                acc[i][j] = __builtin_amdgcn_mfma_f32_16x16x32_bf16(af[i], bfr[j], acc[i][j], 0, 0, 0);
        __syncthreads();
    }

    int mrow = m0 + wm * 64;
#pragma unroll
    for (int i = 0; i < 4; ++i) {
#pragma unroll
        for (int j = 0; j < 4; ++j) {
            int mbase = mrow + i * 16 + quad * 4;
            int n = n0 + wn * 64 + j * 16 + l16;
#pragma unroll
            for (int r = 0; r < 4; ++r) {
                float v = acc[i][j][r];
                v = fmaxf(v, 0.f);
                v = v * v;
                H[(size_t)(mbase + r) * INTER + n] = f2bf(v);
            }
        }
    }
}

// GEMM2: y = h @ down^T (K=8192) + xs @ expert^T (K=2048), fp32 out
__global__ __launch_bounds__(256) void gemm_down_moe(
    const u16* __restrict__ H,   // [NTOK][INTER]
    const u16* __restrict__ XS,  // [NTOK][HID]
    const u16* __restrict__ Dt,  // down^T   [HID][INTER]
    const u16* __restrict__ Et,  // expert^T [HID][HID]
    float* __restrict__ Y)       // [NTOK][HID]
{
    __shared__ u16 As[BM * BK];
    __shared__ u16 Bs[BN * BK];
    int tid = threadIdx.x;
    int wid = tid >> 6, lane = tid & 63;
    int wm = wid >> 1, wn = wid & 1;
    int quad = lane >> 4, l16 = lane & 15;
    int m0 = blockIdx.y * BM, n0 = blockIdx.x * BN;

    int c0 = wid, c1 = wid + 4;
    int ar0 = c0 * 16 + (lane >> 2), ar1 = c1 * 16 + (lane >> 2);
    int ac  = (lane & 3) * 8;

    floatx4 acc[4][4];
#pragma unroll
    for (int i = 0; i < 4; ++i)
#pragma unroll
        for (int j = 0; j < 4; ++j) acc[i][j] = (floatx4){0.f, 0.f, 0.f, 0.f};

    const int KT1 = INTER / BK;              // 256 iters over h/down
    const int KT2 = HID / BK;                // 64 iters over xs/expert
    for (int kt = 0; kt < KT1 + KT2; ++kt) {
        const u16 *Ab, *Bb; int lda, ldb, kk;
        if (kt < KT1) { Ab = H;  lda = INTER; Bb = Dt; ldb = INTER; kk = kt * BK; }
        else          { Ab = XS; lda = HID;   Bb = Et; ldb = HID;   kk = (kt - KT1) * BK; }
        load_lds16(Ab + (size_t)(m0 + ar0) * lda + kk + ac, &As[c0 * 512]);
        load_lds16(Ab + (size_t)(m0 + ar1) * lda + kk + ac, &As[c1 * 512]);
        load_lds16(Bb + (size_t)(n0 + ar0) * ldb + kk + ac, &Bs[c0 * 512]);
        load_lds16(Bb + (size_t)(n0 + ar1) * ldb + kk + ac, &Bs[c1 * 512]);
        __syncthreads();
        bf16x8 af[4], bfr[4];
#pragma unroll
        for (int i = 0; i < 4; ++i)
            af[i] = *(const bf16x8*)(&As[(wm * 64 + i * 16 + l16) * BK + quad * 8]);
#pragma unroll
        for (int j = 0; j < 4; ++j)
            bfr[j] = *(const bf16x8*)(&Bs[(wn * 64 + j * 16 + l16) * BK + quad * 8]);
#pragma unroll
        for (int i = 0; i < 4; ++i)
#pragma unroll
            for (int j = 0; j < 4; ++j)
                acc[i][j] = __builtin_amdgcn_mfma_f32_16x16x32_bf16(af[i], bfr[j], acc[i][j], 0, 0, 0);
        __syncthreads();
    }

    int mrow = m0 + wm * 64;
#pragma unroll
    for (int i = 0; i < 4; ++i) {
#pragma unroll
        for (int j = 0; j < 4; ++j) {
            int mbase = mrow + i * 16 + quad * 4;
            int n = n0 + wn * 64 + j * 16 + l16;
#pragma unroll
            for (int r = 0; r < 4; ++r)
                Y[(size_t)(mbase + r) * HID + n] = acc[i][j][r];
        }
    }
}

// ---------------------------------------------------------------------------
// Kernel 5: LayerNorm in-place over d_out rows
// ---------------------------------------------------------------------------
__global__ __launch_bounds__(256) void ln_kernel(
    float* __restrict__ y, const float* __restrict__ gamma,
    const float* __restrict__ beta)
{
    int token = blockIdx.x;
    int t = threadIdx.x;
    float* yr = y + (size_t)token * HID;
    float4 v0 = ((const float4*)yr)[t];
    float4 v1 = ((const float4*)yr)[t + 256];
    float s  = v0.x + v0.y + v0.z + v0.w + v1.x + v1.y + v1.z + v1.w;
    float ss = v0.x*v0.x + v0.y*v0.y + v0.z*v0.z + v0.w*v0.w
             + v1.x*v1.x + v1.y*v1.y + v1.z*v1.z + v1.w*v1.w;
#pragma unroll
    for (int off = 32; off >= 1; off >>= 1) {
        s  += __shfl_xor(s,  off, 64);
        ss += __shfl_xor(ss, off, 64);
    }
    __shared__ float rs_[4], rss_[4];
    int w = t >> 6, lane = t & 63;
    if (lane == 0) { rs_[w] = s; rss_[w] = ss; }
    __syncthreads();
    s  = rs_[0] + rs_[1] + rs_[2] + rs_[3];
    ss = rss_[0] + rss_[1] + rss_[2] + rss_[3];
    float mu  = s * (1.f / HID);
    float var = ss * (1.f / HID) - mu * mu;
    float rstd = rsqrtf(var + 1e-5f);
    float4 g0 = ((const float4*)gamma)[t];
    float4 g1 = ((const float4*)gamma)[t + 256];
    float4 b0 = ((const float4*)beta)[t];
    float4 b1 = ((const float4*)beta)[t + 256];
    float4 o0, o1;
    o0.x = (v0.x - mu) * rstd * g0.x + b0.x;
    o0.y = (v0.y - mu) * rstd * g0.y + b0.y;
    o0.z = (v0.z - mu) * rstd * g0.z + b0.z;
    o0.w = (v0.w - mu) * rstd * g0.w + b0.w;
    o1.x = (v1.x - mu) * rstd * g1.x + b1.x;
    o1.y = (v1.y - mu) * rstd * g1.y + b1.y;
    o1.z = (v1.z - mu) * rstd * g1.z + b1.z;
    o1.w = (v1.w - mu) * rstd * g1.w + b1.w;
    ((float4*)yr)[t]       = o0;
    ((float4*)yr)[t + 256] = o1;
}

// ---------------------------------------------------------------------------
extern "C" void kernel_launch(void* const* d_in, const int* in_sizes, int n_in,
                              void* d_out, int out_size, void* d_ws, size_t ws_size,
                              hipStream_t stream) {
    const float* x     = (const float*)d_in[0];
    const float* gate  = (const float*)d_in[1];
    const float* up    = (const float*)d_in[2];
    const float* down  = (const float*)d_in[3];
    const float* expw  = (const float*)d_in[4];
    const float* gamma = (const float*)d_in[5];
    const float* beta  = (const float*)d_in[6];
    float* out = (float*)d_out;

    // workspace layout (elements of u16)
    u16* ws  = (u16*)d_ws;
    u16* xb  = ws;                          // 33,554,432  x_bf16
    u16* xsb = xb  + (size_t)NTOK * HID;    // 33,554,432  x*scale bf16
    u16* upT = xsb + (size_t)NTOK * HID;    // 16,777,216  up^T
    u16* dT  = upT + (size_t)INTER * HID;   // 16,777,216  down^T
    u16* eT  = dT  + (size_t)INTER * HID;   //  4,194,304  expert^T
    u16* h   = eT  + (size_t)HID * HID;     // 134,217,728 relu(up(x))^2

    prep_tokens<<<dim3(NTOK / 4), dim3(256), 0, stream>>>(x, gate, xb, xsb);
    transpose_cast<<<dim3(INTER / 32, HID / 32), dim3(256), 0, stream>>>(up, upT, HID, INTER);
    transpose_cast<<<dim3(HID / 32, INTER / 32), dim3(256), 0, stream>>>(down, dT, INTER, HID);
    transpose_cast<<<dim3(HID / 32, HID / 32), dim3(256), 0, stream>>>(expw, eT, HID, HID);
    gemm_up<<<dim3(INTER / BN, NTOK / BM), dim3(256), 0, stream>>>(xb, upT, h);
    gemm_down_moe<<<dim3(HID / BN, NTOK / BM), dim3(256), 0, stream>>>(h, xsb, dT, eT, out);
    ln_kernel<<<dim3(NTOK), dim3(256), 0, stream>>>(out, gamma, beta);
}

// Round 2
// 1921.698 us; speedup vs baseline: 1.0396x; 1.0396x over previous
//
#include <hip/hip_runtime.h>

#define HID   2048
#define INTER 8192
#define NEXP  8
#define NTOK  16384   // 4 * 4096

typedef unsigned short u16;
typedef __bf16 bf16x8 __attribute__((ext_vector_type(8)));
typedef float  floatx4 __attribute__((ext_vector_type(4)));
typedef u16    u16x4   __attribute__((ext_vector_type(4)));

typedef __attribute__((address_space(3))) void       lds_void_t;
typedef const __attribute__((address_space(1))) void gbl_void_t;

__device__ __forceinline__ u16 f2bf(float f) {
    union { float f; unsigned u; } v; v.f = f;
    unsigned r = v.u + 0x7fffu + ((v.u >> 16) & 1u);  // round-to-nearest-even
    return (u16)(r >> 16);
}

__device__ __forceinline__ void load_lds16(const void* g, void* l) {
    __builtin_amdgcn_global_load_lds((gbl_void_t*)g, (lds_void_t*)l, 16, 0, 0);
}

// ---------------------------------------------------------------------------
// Kernel 1: per-token gate logits (fp32) -> top-2 sum scale; write x_bf16 and
// xs_bf16 = x * scale. One wave per token, 4 tokens per block.
// ---------------------------------------------------------------------------
__global__ __launch_bounds__(256) void prep_tokens(
    const float* __restrict__ x, const float* __restrict__ gate,
    u16* __restrict__ xb, u16* __restrict__ xsb)
{
    int token = blockIdx.x * 4 + (threadIdx.x >> 6);
    int lane  = threadIdx.x & 63;
    const float* xr = x + (size_t)token * HID;

    float acc[NEXP];
#pragma unroll
    for (int e = 0; e < NEXP; ++e) acc[e] = 0.f;
#pragma unroll
    for (int c = 0; c < 8; ++c) {
        int kbase = lane * 32 + c * 4;
        float4 v = *(const float4*)(xr + kbase);
        float vv[4] = {v.x, v.y, v.z, v.w};
#pragma unroll
        for (int q = 0; q < 4; ++q) {
            const float* g = gate + (size_t)(kbase + q) * NEXP;
            float4 g0 = *(const float4*)(g);
            float4 g1 = *(const float4*)(g + 4);
            acc[0] += vv[q] * g0.x; acc[1] += vv[q] * g0.y;
            acc[2] += vv[q] * g0.z; acc[3] += vv[q] * g0.w;
            acc[4] += vv[q] * g1.x; acc[5] += vv[q] * g1.y;
            acc[6] += vv[q] * g1.z; acc[7] += vv[q] * g1.w;
        }
    }
#pragma unroll
    for (int off = 32; off >= 1; off >>= 1) {
#pragma unroll
        for (int e = 0; e < NEXP; ++e) acc[e] += __shfl_xor(acc[e], off, 64);
    }
    float m1 = acc[0], m2 = -3.4e38f;
#pragma unroll
    for (int e = 1; e < NEXP; ++e) {
        float v = acc[e];
        if (v > m1) { m2 = m1; m1 = v; } else if (v > m2) { m2 = v; }
    }
    float scale = m1 + m2;

    u16* xo  = xb  + (size_t)token * HID;
    u16* xso = xsb + (size_t)token * HID;
#pragma unroll
    for (int c = 0; c < 8; ++c) {
        int idx = (c * 64 + lane) * 4;
        float4 v = *(const float4*)(xr + idx);
        u16x4 b  = { f2bf(v.x), f2bf(v.y), f2bf(v.z), f2bf(v.w) };
        u16x4 bs = { f2bf(v.x * scale), f2bf(v.y * scale),
                     f2bf(v.z * scale), f2bf(v.w * scale) };
        *(u16x4*)(xo  + idx) = b;
        *(u16x4*)(xso + idx) = bs;
    }
}

// ---------------------------------------------------------------------------
// Kernel 2: transpose + cast  in[K][N] fp32 -> out[N][K] bf16
// ---------------------------------------------------------------------------
__global__ __launch_bounds__(256) void transpose_cast(
    const float* __restrict__ in, u16* __restrict__ out, int K, int N)
{
    __shared__ float t[32][33];
    int tx = threadIdx.x & 31;
    int ty = threadIdx.x >> 5;     // 0..7
    int k0 = blockIdx.y * 32, n0 = blockIdx.x * 32;
#pragma unroll
    for (int r = 0; r < 4; ++r)
        t[ty + r * 8][tx] = in[(size_t)(k0 + ty + r * 8) * N + n0 + tx];
    __syncthreads();
#pragma unroll
    for (int r = 0; r < 4; ++r)
        out[(size_t)(n0 + ty + r * 8) * K + k0 + tx] = f2bf(t[tx][ty + r * 8]);
}

// ---------------------------------------------------------------------------
// GEMM core: BM=BN=128, BK=64 (halves barrier-drain count vs BK=32), 256
// threads (2x2 waves). A[M][K] bf16 row-major, B[N][K] bf16 row-major.
// XOR chunk swizzle on LDS: 16-byte chunk q of row r is stored at slot
// q ^ (r & 7)  -> ds_read_b128 fragments spread over all 32 banks (2-way
// aliasing only = free). global_load_lds writes stay base + lane*16.
// ---------------------------------------------------------------------------
#define BM 128
#define BN 128
#define BK 64

// Per-iteration staging: wave `wid` stages LDS chunk rows. cw in 0..15,
// each cw = 1 KB wave-chunk covering rows [cw*8, cw*8+8), 8x16B chunks/row.
#define STAGE_TILE(dst, srcbase, ld)                                          \
    {                                                                         \
        int cw_ = wid * 4 + j;                                                \
        int row_ = cw_ * 8 + (lane >> 3);                                     \
        int cs_ = (lane & 7) ^ (row_ & 7);                                    \
        load_lds16(srcbase + (size_t)row_ * (ld) + kk + cs_ * 8,              \
                   &dst[cw_ * 512]);                                          \
    }

__device__ __forceinline__ void read_frags(
    const u16* As, const u16* Bs, int wm, int wn, int l16, int quad, int t,
    bf16x8* af, bf16x8* bfr)
{
    int q = t * 4 + quad;
#pragma unroll
    for (int i = 0; i < 4; ++i) {
        int row = wm * 64 + i * 16 + l16;
        af[i] = *(const bf16x8*)(&As[row * BK + (q ^ (row & 7)) * 8]);
    }
#pragma unroll
    for (int j = 0; j < 4; ++j) {
        int row = wn * 64 + j * 16 + l16;
        bfr[j] = *(const bf16x8*)(&Bs[row * BK + (q ^ (row & 7)) * 8]);
    }
}

// GEMM1: h = bf16(relu(x @ up)^2), h[NTOK][INTER]
__global__ __launch_bounds__(256) void gemm_up(
    const u16* __restrict__ A,   // x_bf16 [NTOK][HID]
    const u16* __restrict__ Bt,  // up^T   [INTER][HID]
    u16* __restrict__ H)         // out    [NTOK][INTER]
{
    __shared__ u16 As[BM * BK];
    __shared__ u16 Bs[BN * BK];
    int tid = threadIdx.x;
    int wid = tid >> 6, lane = tid & 63;
    int wm = wid >> 1, wn = wid & 1;
    int quad = lane >> 4, l16 = lane & 15;
    int m0 = blockIdx.y * BM, n0 = blockIdx.x * BN;

    floatx4 acc[4][4];
#pragma unroll
    for (int i = 0; i < 4; ++i)
#pragma unroll
        for (int j = 0; j < 4; ++j) acc[i][j] = (floatx4){0.f, 0.f, 0.f, 0.f};

    const u16* Ab = A  + (size_t)m0 * HID;
    const u16* Bb = Bt + (size_t)n0 * HID;

    for (int kt = 0; kt < HID / BK; ++kt) {
        int kk = kt * BK;
#pragma unroll
        for (int j = 0; j < 4; ++j) {
            STAGE_TILE(As, Ab, HID)
            STAGE_TILE(Bs, Bb, HID)
        }
        __syncthreads();
#pragma unroll
        for (int t = 0; t < 2; ++t) {
            bf16x8 af[4], bfr[4];
            read_frags(As, Bs, wm, wn, l16, quad, t, af, bfr);
#pragma unroll
            for (int i = 0; i < 4; ++i)
#pragma unroll
                for (int j = 0; j < 4; ++j)
                    acc[i][j] = __builtin_amdgcn_mfma_f32_16x16x32_bf16(af[i], bfr[j], acc[i][j], 0, 0, 0);
        }
        __syncthreads();
    }

    int mrow = m0 + wm * 64;
#pragma unroll
    for (int i = 0; i < 4; ++i) {
#pragma unroll
        for (int j = 0; j < 4; ++j) {
            int mbase = mrow + i * 16 + quad * 4;
            int n = n0 + wn * 64 + j * 16 + l16;
#pragma unroll
            for (int r = 0; r < 4; ++r) {
                float v = acc[i][j][r];
                v = fmaxf(v, 0.f);
                v = v * v;
                H[(size_t)(mbase + r) * INTER + n] = f2bf(v);
            }
        }
    }
}

// GEMM2: y = h @ down^T (K=8192) + xs @ expert^T (K=2048), fp32 out
__global__ __launch_bounds__(256) void gemm_down_moe(
    const u16* __restrict__ H,   // [NTOK][INTER]
    const u16* __restrict__ XS,  // [NTOK][HID]
    const u16* __restrict__ Dt,  // down^T   [HID][INTER]
    const u16* __restrict__ Et,  // expert^T [HID][HID]
    float* __restrict__ Y)       // [NTOK][HID]
{
    __shared__ u16 As[BM * BK];
    __shared__ u16 Bs[BN * BK];
    int tid = threadIdx.x;
    int wid = tid >> 6, lane = tid & 63;
    int wm = wid >> 1, wn = wid & 1;
    int quad = lane >> 4, l16 = lane & 15;
    int m0 = blockIdx.y * BM, n0 = blockIdx.x * BN;

    floatx4 acc[4][4];
#pragma unroll
    for (int i = 0; i < 4; ++i)
#pragma unroll
        for (int j = 0; j < 4; ++j) acc[i][j] = (floatx4){0.f, 0.f, 0.f, 0.f};

    const int KT1 = INTER / BK;              // 128 iters over h/down
    const int KT2 = HID / BK;                // 32 iters over xs/expert
    for (int kt = 0; kt < KT1 + KT2; ++kt) {
        const u16 *Ab, *Bb; int lda, ldb, kk;
        if (kt < KT1) {
            Ab = H  + (size_t)m0 * INTER; lda = INTER;
            Bb = Dt + (size_t)n0 * INTER; ldb = INTER; kk = kt * BK;
        } else {
            Ab = XS + (size_t)m0 * HID;   lda = HID;
            Bb = Et + (size_t)n0 * HID;   ldb = HID;   kk = (kt - KT1) * BK;
        }
#pragma unroll
        for (int j = 0; j < 4; ++j) {
            STAGE_TILE(As, Ab, lda)
            STAGE_TILE(Bs, Bb, ldb)
        }
        __syncthreads();
#pragma unroll
        for (int t = 0; t < 2; ++t) {
            bf16x8 af[4], bfr[4];
            read_frags(As, Bs, wm, wn, l16, quad, t, af, bfr);
#pragma unroll
            for (int i = 0; i < 4; ++i)
#pragma unroll
                for (int j = 0; j < 4; ++j)
                    acc[i][j] = __builtin_amdgcn_mfma_f32_16x16x32_bf16(af[i], bfr[j], acc[i][j], 0, 0, 0);
        }
        __syncthreads();
    }

    int mrow = m0 + wm * 64;
#pragma unroll
    for (int i = 0; i < 4; ++i) {
#pragma unroll
        for (int j = 0; j < 4; ++j) {
            int mbase = mrow + i * 16 + quad * 4;
            int n = n0 + wn * 64 + j * 16 + l16;
#pragma unroll
            for (int r = 0; r < 4; ++r)
                Y[(size_t)(mbase + r) * HID + n] = acc[i][j][r];
        }
    }
}

// ---------------------------------------------------------------------------
// Kernel 5: LayerNorm in-place over d_out rows
// ---------------------------------------------------------------------------
__global__ __launch_bounds__(256) void ln_kernel(
    float* __restrict__ y, const float* __restrict__ gamma,
    const float* __restrict__ beta)
{
    int token = blockIdx.x;
    int t = threadIdx.x;
    float* yr = y + (size_t)token * HID;
    float4 v0 = ((const float4*)yr)[t];
    float4 v1 = ((const float4*)yr)[t + 256];
    float s  = v0.x + v0.y + v0.z + v0.w + v1.x + v1.y + v1.z + v1.w;
    float ss = v0.x*v0.x + v0.y*v0.y + v0.z*v0.z + v0.w*v0.w
             + v1.x*v1.x + v1.y*v1.y + v1.z*v1.z + v1.w*v1.w;
#pragma unroll
    for (int off = 32; off >= 1; off >>= 1) {
        s  += __shfl_xor(s,  off, 64);
        ss += __shfl_xor(ss, off, 64);
    }
    __shared__ float rs_[4], rss_[4];
    int w = t >> 6, lane = t & 63;
    if (lane == 0) { rs_[w] = s; rss_[w] = ss; }
    __syncthreads();
    s  = rs_[0] + rs_[1] + rs_[2] + rs_[3];
    ss = rss_[0] + rss_[1] + rss_[2] + rss_[3];
    float mu  = s * (1.f / HID);
    float var = ss * (1.f / HID) - mu * mu;
    float rstd = rsqrtf(var + 1e-5f);
    float4 g0 = ((const float4*)gamma)[t];
    float4 g1 = ((const float4*)gamma)[t + 256];
    float4 b0 = ((const float4*)beta)[t];
    float4 b1 = ((const float4*)beta)[t + 256];
    float4 o0, o1;
    o0.x = (v0.x - mu) * rstd * g0.x + b0.x;
    o0.y = (v0.y - mu) * rstd * g0.y + b0.y;
    o0.z = (v0.z - mu) * rstd * g0.z + b0.z;
    o0.w = (v0.w - mu) * rstd * g0.w + b0.w;
    o1.x = (v1.x - mu) * rstd * g1.x + b1.x;
    o1.y = (v1.y - mu) * rstd * g1.y + b1.y;
    o1.z = (v1.z - mu) * rstd * g1.z + b1.z;
    o1.w = (v1.w - mu) * rstd * g1.w + b1.w;
    ((float4*)yr)[t]       = o0;
    ((float4*)yr)[t + 256] = o1;
}

// ---------------------------------------------------------------------------
extern "C" void kernel_launch(void* const* d_in, const int* in_sizes, int n_in,
                              void* d_out, int out_size, void* d_ws, size_t ws_size,
                              hipStream_t stream) {
    const float* x     = (const float*)d_in[0];
    const float* gate  = (const float*)d_in[1];
    const float* up    = (const float*)d_in[2];
    const float* down  = (const float*)d_in[3];
    const float* expw  = (const float*)d_in[4];
    const float* gamma = (const float*)d_in[5];
    const float* beta  = (const float*)d_in[6];
    float* out = (float*)d_out;

    // workspace layout (elements of u16)
    u16* ws  = (u16*)d_ws;
    u16* xb  = ws;                          // 33,554,432  x_bf16
    u16* xsb = xb  + (size_t)NTOK * HID;    // 33,554,432  x*scale bf16
    u16* upT = xsb + (size_t)NTOK * HID;    // 16,777,216  up^T
    u16* dT  = upT + (size_t)INTER * HID;   // 16,777,216  down^T
    u16* eT  = dT  + (size_t)INTER * HID;   //  4,194,304  expert^T
    u16* h   = eT  + (size_t)HID * HID;     // 134,217,728 relu(up(x))^2

    prep_tokens<<<dim3(NTOK / 4), dim3(256), 0, stream>>>(x, gate, xb, xsb);
    transpose_cast<<<dim3(INTER / 32, HID / 32), dim3(256), 0, stream>>>(up, upT, HID, INTER);
    transpose_cast<<<dim3(HID / 32, INTER / 32), dim3(256), 0, stream>>>(down, dT, INTER, HID);
    transpose_cast<<<dim3(HID / 32, HID / 32), dim3(256), 0, stream>>>(expw, eT, HID, HID);
    gemm_up<<<dim3(INTER / BN, NTOK / BM), dim3(256), 0, stream>>>(xb, upT, h);
    gemm_down_moe<<<dim3(HID / BN, NTOK / BM), dim3(256), 0, stream>>>(h, xsb, dT, eT, out);
    ln_kernel<<<dim3(NTOK), dim3(256), 0, stream>>>(out, gamma, beta);
}